// Round 7
// baseline (527.177 us; speedup 1.0000x reference)
//
#include <hip/hip_runtime.h>

#define N_NODES 100000
#define N_EDGES 1600000
#define D_FEAT  32

// ---- partition parameters ----
#define NBINS     512
#define BIN_NODES 196                 // 512*196 = 100352 >= 100000
#define NBLK1     256                 // partition blocks
#define BLK1_T    512
#define CHUNK1    ((N_EDGES + NBLK1 - 1) / NBLK1)   // 6250 edges / block
#define SEGCAP    48                  // per-(block,bin) capacity; mean 12.2, P(ovf)~1e-9
#define BLK2_T    512

// ============ K1: partition into private (block,bin) segments ============
// Private sequential segments -> writeback ~= payload (kills the ~1 TB/s
// scattered-dirty-line ceiling measured in rounds 1/3/4). ~30us in round 6.
__global__ __launch_bounds__(BLK1_T) void partition_kernel(
    const int* __restrict__ src,
    const int* __restrict__ dst,
    int2* __restrict__ recs,          // [NBLK1 * NBINS * SEGCAP]
    int*  __restrict__ cnt)           // [NBINS * NBLK1]
{
    __shared__ int cur[NBINS];
    const int blk = blockIdx.x, tid = threadIdx.x;
    for (int i = tid; i < NBINS; i += BLK1_T) cur[i] = 0;
    __syncthreads();

    const int e0 = blk * CHUNK1;
    const int e1 = min(e0 + CHUNK1, N_EDGES);
    for (int e = e0 + tid; e < e1; e += BLK1_T) {
        int d = dst[e];
        int s = src[e];
        int b  = (int)((unsigned)d / BIN_NODES);
        int ld = d - b * BIN_NODES;                  // 0..195
        int slot = atomicAdd(&cur[b], 1);
        if (slot < SEGCAP) {
            // word0: e (21 bits) | ld (8 bits) << 21 ; word1: src
            recs[(size_t)(blk * NBINS + b) * SEGCAP + slot] =
                make_int2((int)((unsigned)e | ((unsigned)ld << 21)), s);
        }
    }
    __syncthreads();
    for (int b = tid; b < NBINS; b += BLK1_T)
        cnt[b * NBLK1 + blk] = min(cur[b], SEGCAP);
}

// ============ K2: per-bin LDS-accumulated gather ============
// Grid 512 (2 blocks/CU, 16 waves/CU). Run-per-WAVE: halves process
// even/odd records of the SAME run -> wave-uniform loop bounds, scalar cnt.
// Records prefetched one group (8 recs) ahead so row loads overlap across
// groups. acc ds_add: 32 banks, 2 lanes/bank -> conflict-free (m136).
__global__ __launch_bounds__(BLK2_T, 4) void binned_gather_kernel(
    const float*  __restrict__ rel,
    const float*  __restrict__ pattern,
    const int2*   __restrict__ recs,
    const int*    __restrict__ cnt,
    const float4* __restrict__ rel4,
    float4* __restrict__ out4)
{
    __shared__ float acc[BIN_NODES * D_FEAT];   // 25,088 B
    __shared__ int   degl[BIN_NODES];

    const int b   = blockIdx.x;
    const int tid = threadIdx.x;
    for (int i = tid; i < BIN_NODES * D_FEAT; i += BLK2_T) acc[i] = 0.0f;
    for (int i = tid; i < BIN_NODES; i += BLK2_T) degl[i] = 0;
    __syncthreads();

    const int wv   = tid >> 6;         // wave 0..7
    const int half = (tid >> 5) & 1;   // half-wave within wave
    const int f    = tid & 31;         // feature lane

    for (int r = wv; r < NBLK1; r += 8) {
        const int m = cnt[b * NBLK1 + r];                      // wave-uniform
        const int4* rp4 = (const int4*)(recs + (size_t)(r * NBINS + b) * SEGCAP);

        // A..D hold records k..k+7 (2 records per int4; half selects even/odd)
        int4 A = rp4[0], B = rp4[1], C = rp4[2], D = rp4[3];
        int k = 0;
        for (; k + 8 <= m; k += 8) {
            int4 nA = rp4[(k >> 1) + 4], nB = rp4[(k >> 1) + 5];
            int4 nC = rp4[(k >> 1) + 6], nD = rp4[(k >> 1) + 7];
            unsigned w0 = (unsigned)(half ? A.z : A.x); int s0 = half ? A.w : A.y;
            unsigned w1 = (unsigned)(half ? B.z : B.x); int s1 = half ? B.w : B.y;
            unsigned w2 = (unsigned)(half ? C.z : C.x); int s2 = half ? C.w : C.y;
            unsigned w3 = (unsigned)(half ? D.z : D.x); int s3 = half ? D.w : D.y;
            int e0 = w0 & 0x1FFFFF, l0 = w0 >> 21;
            int e1 = w1 & 0x1FFFFF, l1 = w1 >> 21;
            int e2 = w2 & 0x1FFFFF, l2 = w2 >> 21;
            int e3 = w3 & 0x1FFFFF, l3 = w3 >> 21;
            float p0 = pattern[e0 * D_FEAT + f], a0 = rel[s0 * D_FEAT + f];
            float p1 = pattern[e1 * D_FEAT + f], a1 = rel[s1 * D_FEAT + f];
            float p2 = pattern[e2 * D_FEAT + f], a2 = rel[s2 * D_FEAT + f];
            float p3 = pattern[e3 * D_FEAT + f], a3 = rel[s3 * D_FEAT + f];
            if (f == 0) {
                atomicAdd(&degl[l0], 1); atomicAdd(&degl[l1], 1);
                atomicAdd(&degl[l2], 1); atomicAdd(&degl[l3], 1);
            }
            atomicAdd(&acc[l0 * D_FEAT + f], p0 * a0);
            atomicAdd(&acc[l1 * D_FEAT + f], p1 * a1);
            atomicAdd(&acc[l2 * D_FEAT + f], p2 * a2);
            atomicAdd(&acc[l3 * D_FEAT + f], p3 * a3);
            A = nA; B = nB; C = nC; D = nD;
        }
        // tail: records k..m-1 live in A..D; my half's record j has parity half
        int rem = m - k;
        if (half + 0 < rem) {
            unsigned w = (unsigned)(half ? A.z : A.x); int s = half ? A.w : A.y;
            int e = w & 0x1FFFFF, l = w >> 21;
            float v = pattern[e * D_FEAT + f] * rel[s * D_FEAT + f];
            if (f == 0) atomicAdd(&degl[l], 1);
            atomicAdd(&acc[l * D_FEAT + f], v);
        }
        if (half + 2 < rem) {
            unsigned w = (unsigned)(half ? B.z : B.x); int s = half ? B.w : B.y;
            int e = w & 0x1FFFFF, l = w >> 21;
            float v = pattern[e * D_FEAT + f] * rel[s * D_FEAT + f];
            if (f == 0) atomicAdd(&degl[l], 1);
            atomicAdd(&acc[l * D_FEAT + f], v);
        }
        if (half + 4 < rem) {
            unsigned w = (unsigned)(half ? C.z : C.x); int s = half ? C.w : C.y;
            int e = w & 0x1FFFFF, l = w >> 21;
            float v = pattern[e * D_FEAT + f] * rel[s * D_FEAT + f];
            if (f == 0) atomicAdd(&degl[l], 1);
            atomicAdd(&acc[l * D_FEAT + f], v);
        }
        if (half + 6 < rem) {
            unsigned w = (unsigned)(half ? D.z : D.x); int s = half ? D.w : D.y;
            int e = w & 0x1FFFFF, l = w >> 21;
            float v = pattern[e * D_FEAT + f] * rel[s * D_FEAT + f];
            if (f == 0) atomicAdd(&degl[l], 1);
            atomicAdd(&acc[l * D_FEAT + f], v);
        }
    }
    __syncthreads();

    // epilogue: out = acc/max(deg,1) + rel, coalesced float4
    const int node0 = b * BIN_NODES;
    const int nNodes = min(BIN_NODES, N_NODES - node0);
    for (int i = tid; i < nNodes * 8; i += BLK2_T) {
        int ld = i >> 3, q = i & 7;
        float4 a = *(const float4*)&acc[ld * D_FEAT + q * 4];
        float inv = 1.0f / fmaxf((float)degl[ld], 1.0f);
        int node = node0 + ld;
        float4 rl = rel4[node * 8 + q];
        float4 o;
        o.x = a.x * inv + rl.x;
        o.y = a.y * inv + rl.y;
        o.z = a.z * inv + rl.z;
        o.w = a.w * inv + rl.w;
        out4[node * 8 + q] = o;
    }
}

// ---- atomic fallback (round-1, known-correct; needs only 400 KB ws) ----
__global__ void sage_edge_atomic_kernel(const float* __restrict__ rel,
                                        const float* __restrict__ pattern,
                                        const int*   __restrict__ src,
                                        const int*   __restrict__ dst,
                                        float* __restrict__ sums,
                                        float* __restrict__ deg) {
    int i = blockIdx.x * blockDim.x + threadIdx.x;
    if (i >= N_EDGES * D_FEAT) return;
    int e = i >> 5;
    int f = i & 31;
    float m = rel[src[e] * D_FEAT + f] * pattern[i];
    atomicAdd(&sums[dst[e] * D_FEAT + f], m);
    if (f == 0) atomicAdd(&deg[dst[e]], 1.0f);
}

__global__ void sage_node_atomic_kernel(const float* __restrict__ rel,
                                        const float* __restrict__ deg,
                                        float* __restrict__ out) {
    int i = blockIdx.x * blockDim.x + threadIdx.x;
    if (i >= N_NODES * D_FEAT) return;
    out[i] = out[i] / fmaxf(deg[i >> 5], 1.0f) + rel[i];
}

extern "C" void kernel_launch(void* const* d_in, const int* in_sizes, int n_in,
                              void* d_out, int out_size, void* d_ws, size_t ws_size,
                              hipStream_t stream) {
    const float* rel     = (const float*)d_in[0];
    const float* pattern = (const float*)d_in[1];
    const int*   src     = (const int*)d_in[2];
    const int*   dst     = (const int*)d_in[3];
    float* out = (float*)d_out;

    const size_t recs_bytes = (size_t)NBLK1 * NBINS * SEGCAP * sizeof(int2); // 50.3 MB
    const size_t cnt_bytes  = (size_t)NBINS * NBLK1 * sizeof(int);           // 512 KB
    const size_t need = recs_bytes + 64 /*prefetch pad*/ + cnt_bytes;

    if (ws_size >= need) {
        int2* recs = (int2*)d_ws;
        int*  cnt  = (int*)((char*)d_ws + recs_bytes + 64);

        partition_kernel<<<NBLK1, BLK1_T, 0, stream>>>(src, dst, recs, cnt);
        binned_gather_kernel<<<NBINS, BLK2_T, 0, stream>>>(
            rel, pattern, recs, cnt, (const float4*)rel, (float4*)out);
    } else {
        float* deg = (float*)d_ws;
        hipMemsetAsync(out, 0, sizeof(float) * N_NODES * D_FEAT, stream);
        hipMemsetAsync(deg, 0, sizeof(float) * N_NODES, stream);
        sage_edge_atomic_kernel<<<(N_EDGES * D_FEAT + 255) / 256, 256, 0, stream>>>(
            rel, pattern, src, dst, out, deg);
        sage_node_atomic_kernel<<<(N_NODES * D_FEAT + 255) / 256, 256, 0, stream>>>(
            rel, deg, out);
    }
}